// Round 1
// baseline (368.379 us; speedup 1.0000x reference)
//
#include <hip/hip_runtime.h>

// SegmentTree scatter-update + path propagation.
// capacity = 2^23, n_updates = 2^20, tree buffer = 2*capacity floats (64 MiB).
//
// Structure:
//   1. D2D copy tree_values -> d_out (untouched nodes must keep old values;
//      the input tree is random, NOT a consistent sum tree, so we may only
//      recompute nodes on updated paths).
//   2. Scatter: out[capacity + idx[i]] = val[i].
//   3. 23 level kernels: p = (capacity+idx[i]) >> L; out[p] = out[2p]+out[2p+1].
//      Within a level, duplicate p's write identical values (children are
//      finalized by the previous kernel; read-set level L-1 and write-set
//      level L are disjoint index ranges). Stream ordering = level barrier.

__global__ void scatter_kernel(const int* __restrict__ idx,
                               const float* __restrict__ val,
                               float* __restrict__ out,
                               int capacity, int n) {
    int i = blockIdx.x * blockDim.x + threadIdx.x;
    if (i < n) {
        out[capacity + idx[i]] = val[i];
    }
}

__global__ void level_kernel(const int* __restrict__ idx,
                             float* __restrict__ out,
                             int capacity, int n, int shift) {
    int i = blockIdx.x * blockDim.x + threadIdx.x;
    if (i < n) {
        int p = (capacity + idx[i]) >> shift;
        out[p] = out[2 * p] + out[2 * p + 1];
    }
}

extern "C" void kernel_launch(void* const* d_in, const int* in_sizes, int n_in,
                              void* d_out, int out_size, void* d_ws, size_t ws_size,
                              hipStream_t stream) {
    const float* tree    = (const float*)d_in[0];
    const int*   indices = (const int*)d_in[1];
    const float* values  = (const float*)d_in[2];
    float* out = (float*)d_out;

    const int two_cap  = in_sizes[0];        // 16,777,216
    const int capacity = two_cap >> 1;       // 8,388,608
    const int n_upd    = in_sizes[1];        // 1,048,576

    int depth = 0;
    while ((1 << depth) < capacity) depth++; // 23

    // 1. Copy the whole tree (64 MiB) into the output buffer.
    hipMemcpyAsync(out, tree, (size_t)two_cap * sizeof(float),
                   hipMemcpyDeviceToDevice, stream);

    const int threads = 256;
    const int blocks  = (n_upd + threads - 1) / threads;

    // 2. Scatter leaf updates.
    scatter_kernel<<<blocks, threads, 0, stream>>>(indices, values, out,
                                                   capacity, n_upd);

    // 3. Propagate level by level up to the root.
    for (int L = 1; L <= depth; ++L) {
        level_kernel<<<blocks, threads, 0, stream>>>(indices, out,
                                                     capacity, n_upd, L);
    }
}

// Round 2
// 351.998 us; speedup vs baseline: 1.0465x; 1.0465x over previous
//
#include <hip/hip_runtime.h>

// SegmentTree scatter-update + path propagation, dirty-bitmap version.
// capacity = 2^23, n_updates = 2^20, tree buffer = 2*capacity floats (64 MiB).
//
// d_ws layout: uint32 bitmap, 1 bit per tree node (2*capacity bits = 2 MiB).
// bit p set <=> node p is on an updated path (must be recomputed).
//
// Pipeline:
//   1. copy_clear: out = tree (float4 grid-stride), bitmap = 0.
//   2. scatter:    out[cap+idx] = val; atomicOr leaf dirty bit.
//   3. level_words (levels with M = cap>>L > 8192 parents): one thread per 32
//      parents. Child dirty word pair -> pair-OR -> even-bit compress -> parent
//      word (exclusive, non-atomic). For each set bit: out[p] = out[2p]+out[2p+1]
//      (float2 load, children contiguous per word -> coalesced).
//   4. tail: single block, all remaining levels (<=8192 parents, 16383 nodes
//      total) with __syncthreads between levels; last 5 levels by thread 0 in
//      registers.
// Duplicate-free by construction; math identical to reference -> absmax 0.

typedef unsigned int uint;

// bit j of result = (c bit 2j) | (c bit 2j+1)   (even-bit compress of c|c>>1)
__device__ __forceinline__ uint pair_or_compress(uint c) {
    uint x = (c | (c >> 1)) & 0x55555555u;
    x = (x | (x >> 1)) & 0x33333333u;
    x = (x | (x >> 2)) & 0x0F0F0F0Fu;
    x = (x | (x >> 4)) & 0x00FF00FFu;
    x = (x | (x >> 8)) & 0x0000FFFFu;
    return x;
}

__global__ void copy_clear_kernel(const float4* __restrict__ in,
                                  float4* __restrict__ out,
                                  uint* __restrict__ bm,
                                  int n4, int nbmw) {
    int gid = blockIdx.x * blockDim.x + threadIdx.x;
    int stride = gridDim.x * blockDim.x;
    for (int i = gid; i < n4; i += stride) out[i] = in[i];
    for (int i = gid; i < nbmw; i += stride) bm[i] = 0u;
}

__global__ void scatter_kernel(const int* __restrict__ idx,
                               const float* __restrict__ val,
                               float* __restrict__ out,
                               uint* __restrict__ bm,
                               int capacity, int n) {
    int i = blockIdx.x * blockDim.x + threadIdx.x;
    if (i < n) {
        int leaf = capacity + idx[i];
        out[leaf] = val[i];
        atomicOr(&bm[leaf >> 5], 1u << (leaf & 31));
    }
}

// Parents [32*(wbase+t), 32*(wbase+t)+32) for t in [0, nw).
__global__ void level_words_kernel(float* __restrict__ out,
                                   uint* __restrict__ bm,
                                   int wbase, int nw) {
    int t = blockIdx.x * blockDim.x + threadIdx.x;
    if (t >= nw) return;
    int w = wbase + t;
    uint c0 = bm[2 * w];
    uint c1 = bm[2 * w + 1];
    uint m = pair_or_compress(c0) | (pair_or_compress(c1) << 16);
    bm[w] = m;  // exclusive owner of this word at this level
    int base = 32 * w;
    while (m) {
        int j = __ffs(m) - 1;
        m &= m - 1;
        int p = base + j;
        float2 ch = *(const float2*)&out[2 * p];
        out[p] = ch.x + ch.y;
    }
}

// Single block; handles every level with parent count <= startM.
__global__ void tail_kernel(float* __restrict__ out,
                            uint* __restrict__ bm,
                            int startM) {
    for (int M = startM; M >= 32; M >>= 1) {
        int nw = M >> 5;   // words at this parent level; wbase == nw
        for (int t = threadIdx.x; t < nw; t += blockDim.x) {
            int w = nw + t;
            uint c0 = bm[2 * w];
            uint c1 = bm[2 * w + 1];
            uint m = pair_or_compress(c0) | (pair_or_compress(c1) << 16);
            bm[w] = m;
            int base = 32 * w;
            while (m) {
                int j = __ffs(m) - 1;
                m &= m - 1;
                int p = base + j;
                float2 ch = *(const float2*)&out[2 * p];
                out[p] = ch.x + ch.y;
            }
        }
        __syncthreads();
    }
    // Levels with <32 parents: nodes [16,32), [8,16), ..., [1,2). All masks fit
    // in registers of thread 0. Children of [16,32) are nodes [32,64) = bm[1].
    if (threadIdx.x == 0) {
        uint m = pair_or_compress(bm[1]);  // bit j <-> parent 16+j
        for (int M = 16; M >= 1; M >>= 1) {
            uint mm = m;
            while (mm) {
                int j = __ffs(mm) - 1;
                mm &= mm - 1;
                int p = M + j;
                float2 ch = *(const float2*)&out[2 * p];
                out[p] = ch.x + ch.y;
            }
            m = pair_or_compress(m);
        }
    }
}

extern "C" void kernel_launch(void* const* d_in, const int* in_sizes, int n_in,
                              void* d_out, int out_size, void* d_ws, size_t ws_size,
                              hipStream_t stream) {
    const float* tree    = (const float*)d_in[0];
    const int*   indices = (const int*)d_in[1];
    const float* values  = (const float*)d_in[2];
    float* out = (float*)d_out;
    uint*  bm  = (uint*)d_ws;

    const int two_cap  = in_sizes[0];        // 16,777,216
    const int capacity = two_cap >> 1;       // 8,388,608
    const int n_upd    = in_sizes[1];        // 1,048,576

    const int n4   = two_cap >> 2;           // float4 count
    const int nbmw = two_cap >> 5;           // bitmap words (2 MiB)

    // 1. Copy tree -> out, zero bitmap. 130 MB of traffic: the HBM floor.
    copy_clear_kernel<<<2048, 256, 0, stream>>>((const float4*)tree,
                                                (float4*)out, bm, n4, nbmw);

    // 2. Scatter leaf updates + mark dirty bits.
    scatter_kernel<<<(n_upd + 255) / 256, 256, 0, stream>>>(indices, values,
                                                            out, bm,
                                                            capacity, n_upd);

    // 3. Big levels: one thread per 32 parents.
    int M = capacity >> 1;                   // parents at level 1
    while (M > 8192) {
        int nw = M >> 5;                     // wbase == nw (parents [M, 2M))
        int blocks = (nw + 255) / 256;
        level_words_kernel<<<blocks, 256, 0, stream>>>(out, bm, nw, nw);
        M >>= 1;
    }

    // 4. Remaining levels (M <= 8192, 16383 nodes total): one block.
    tail_kernel<<<1, 1024, 0, stream>>>(out, bm, M);
}

// Round 3
// 220.123 us; speedup vs baseline: 1.6735x; 1.5991x over previous
//
#include <hip/hip_runtime.h>

// SegmentTree scatter-update + path propagation, thread-per-parent + ballot.
// capacity = 2^23, n_updates = 2^20, tree = 2*capacity floats (64 MiB).
//
// d_ws: uint32 dirty bitmap, 1 bit per tree node (2 MiB).
//
// Pipeline:
//   1. copy_clear: out = tree (float4), bitmap = 0.
//   2. scatter:    out[cap+idx] = val; atomicOr leaf dirty bit.
//   3. level kernels (thread per parent, M = cap>>L parents, M >= 8192):
//      dirty = 2 child bits from bm; predicated out[p] = out[2p]+out[2p+1]
//      (coalesced float2); parent bitmap word via wave __ballot (64 parents
//      per wave = 2 aligned words, lanes 0/32 write — no atomics, no loops).
//   4. tail: one block, levels M <= 4096 with same ballot scheme +
//      __syncthreads; last 31 nodes (M<=16) serial on thread 0.
// Math identical to reference (dedup'd recompute of identical values) -> absmax 0.

typedef unsigned int uint;

// bit j of result = (c bit 2j) | (c bit 2j+1)
__device__ __forceinline__ uint pair_or_compress(uint c) {
    uint x = (c | (c >> 1)) & 0x55555555u;
    x = (x | (x >> 1)) & 0x33333333u;
    x = (x | (x >> 2)) & 0x0F0F0F0Fu;
    x = (x | (x >> 4)) & 0x00FF00FFu;
    x = (x | (x >> 8)) & 0x0000FFFFu;
    return x;
}

__global__ void copy_clear_kernel(const float4* __restrict__ in,
                                  float4* __restrict__ out,
                                  uint* __restrict__ bm,
                                  int n4, int nbmw) {
    int gid = blockIdx.x * blockDim.x + threadIdx.x;
    int stride = gridDim.x * blockDim.x;
    for (int i = gid; i < n4; i += stride) out[i] = in[i];
    for (int i = gid; i < nbmw; i += stride) bm[i] = 0u;
}

__global__ void scatter_kernel(const int* __restrict__ idx,
                               const float* __restrict__ val,
                               float* __restrict__ out,
                               uint* __restrict__ bm,
                               int capacity, int n) {
    int i = blockIdx.x * blockDim.x + threadIdx.x;
    if (i < n) {
        int leaf = capacity + idx[i];
        out[leaf] = val[i];
        atomicOr(&bm[leaf >> 5], 1u << (leaf & 31));
    }
}

// One thread per parent p in [M, 2M). M >= 8192 (multiple of 256 -> full waves).
__global__ void level_kernel(float* __restrict__ out,
                             uint* __restrict__ bm, int M) {
    int t = blockIdx.x * blockDim.x + threadIdx.x;
    if (t >= M) return;
    int p = M + t;
    // children 2p, 2p+1 -> bits (2p)&31, +1 of word p>>4 (never straddles)
    uint dirty = (bm[p >> 4] >> ((2 * p) & 31)) & 3u;
    unsigned long long mask = __ballot(dirty != 0);
    if (dirty) {
        float2 ch = *(const float2*)&out[2 * p];
        out[p] = ch.x + ch.y;
    }
    int lane = threadIdx.x & 63;
    if (lane == 0)       bm[p >> 5] = (uint)mask;         // parents p..p+31
    else if (lane == 32) bm[p >> 5] = (uint)(mask >> 32); // parents p..p+31
}

// One block; levels M = startM down to 1.
__global__ void tail_kernel(float* __restrict__ out,
                            uint* __restrict__ bm, int startM) {
    for (int M = startM; M >= 64; M >>= 1) {
        for (int t = threadIdx.x; t < M; t += blockDim.x) {
            int p = M + t;
            uint dirty = (bm[p >> 4] >> ((2 * p) & 31)) & 3u;
            unsigned long long mask = __ballot(dirty != 0);
            if (dirty) {
                float2 ch = *(const float2*)&out[2 * p];
                out[p] = ch.x + ch.y;
            }
            int lane = threadIdx.x & 63;
            if (lane == 0)       bm[p >> 5] = (uint)mask;
            else if (lane == 32) bm[p >> 5] = (uint)(mask >> 32);
        }
        __syncthreads();
    }
    // M = 32: parents [32,64) = word 1. Only wave 0's low half active ->
    // ballot bits 32..63 are 0, low 32 bits are exactly this level's mask.
    if (threadIdx.x < 32) {
        int p = 32 + threadIdx.x;
        uint dirty = (bm[p >> 4] >> ((2 * p) & 31)) & 3u;
        unsigned long long mask = __ballot(dirty != 0);
        if (dirty) {
            float2 ch = *(const float2*)&out[2 * p];
            out[p] = ch.x + ch.y;
        }
        if (threadIdx.x == 0) bm[1] = (uint)mask;
    }
    __syncthreads();
    // M <= 16: 31 nodes, serial on thread 0, masks cascade in registers.
    if (threadIdx.x == 0) {
        uint m = pair_or_compress(bm[1]);  // bit j <-> parent 16+j
        for (int M2 = 16; M2 >= 1; M2 >>= 1) {
            uint mm = m;
            while (mm) {
                int j = __ffs(mm) - 1;
                mm &= mm - 1;
                int p = M2 + j;
                float2 ch = *(const float2*)&out[2 * p];
                out[p] = ch.x + ch.y;
            }
            m = pair_or_compress(m);
        }
    }
}

extern "C" void kernel_launch(void* const* d_in, const int* in_sizes, int n_in,
                              void* d_out, int out_size, void* d_ws, size_t ws_size,
                              hipStream_t stream) {
    const float* tree    = (const float*)d_in[0];
    const int*   indices = (const int*)d_in[1];
    const float* values  = (const float*)d_in[2];
    float* out = (float*)d_out;
    uint*  bm  = (uint*)d_ws;

    const int two_cap  = in_sizes[0];        // 16,777,216
    const int capacity = two_cap >> 1;       // 8,388,608
    const int n_upd    = in_sizes[1];        // 1,048,576

    const int n4   = two_cap >> 2;
    const int nbmw = two_cap >> 5;

    // 1. 128 MB copy + 2 MB clear: the HBM floor (~21 us).
    copy_clear_kernel<<<4096, 256, 0, stream>>>((const float4*)tree,
                                                (float4*)out, bm, n4, nbmw);

    // 2. Scatter leaf updates + dirty bits.
    scatter_kernel<<<(n_upd + 255) / 256, 256, 0, stream>>>(indices, values,
                                                            out, bm,
                                                            capacity, n_upd);

    // 3. Levels with M >= 8192 parents: thread per parent.
    for (int M = capacity >> 1; M >= 8192; M >>= 1) {
        level_kernel<<<(M + 255) / 256, 256, 0, stream>>>(out, bm, M);
    }

    // 4. Levels M <= 4096 (8191 nodes): one block.
    tail_kernel<<<1, 1024, 0, stream>>>(out, bm, 4096);
}

// Round 4
// 165.484 us; speedup vs baseline: 2.2261x; 1.3302x over previous
//
#include <hip/hip_runtime.h>

// SegmentTree scatter-update + path propagation — single-pass fused version.
// capacity C = 2^23, n_updates = 2^20, tree = 2C floats (64 MiB).
//
// d_ws layout:
//   [0, 4C)        overlay  float[C]  — scattered new leaf values (by leaf idx)
//   [4C, 5C)       flags    uchar[C]  — 1 if leaf updated (memset 0 each call)
//   [5C, 5C+C/2048) l11flag uchar[4096] — per-block L11 dirty (fully rewritten)
//
// Pipeline (4 dispatches):
//   1. hipMemsetAsync(flags, 0)            — 8 MB
//   2. scatter: overlay[idx]=val; flags[idx]=1 (plain stores, no atomics)
//   3. merge:   thread = depth-3 subtree over 8 leaves: select leaf values
//      (overlay vs tree), write leaves, compute L1/L2/L3 in registers
//      (clean nodes copied from tree); block = 2048-leaf subtree: L4..L11
//      reduced through LDS. Tree bytes read once, out written once.
//   4. tail: one block, L12..L23 (4095 nodes) in LDS; out[0]=tree[0].
// Exact same pairwise sums as reference -> absmax 0.

typedef unsigned int uint;
typedef unsigned char uchar;

__global__ void scatter_kernel(const int* __restrict__ idx,
                               const float* __restrict__ val,
                               float* __restrict__ overlay,
                               uchar* __restrict__ flags, int n) {
    int i = blockIdx.x * blockDim.x + threadIdx.x;
    if (i < n) {
        int j = idx[i];
        overlay[j] = val[i];
        flags[j] = 1;
    }
}

__global__ __launch_bounds__(256)
void merge_kernel(const float* __restrict__ tree,
                  const float* __restrict__ overlay,
                  const uchar* __restrict__ flags,
                  uchar* __restrict__ l11flag,
                  float* __restrict__ out, int C) {
    const int t = blockIdx.x * 256 + threadIdx.x;   // 0 .. C/8-1
    const int leaf0 = t * 8;

    // ---- leaves: select overlay vs tree, write out ----
    const float4* tl = (const float4*)(tree + C + leaf0);
    float4 ta = tl[0], tb = tl[1];
    const float4* op = (const float4*)(overlay + leaf0);
    float4 oa = op[0], ob = op[1];      // garbage where clean — never selected
    uint2 f = *(const uint2*)(flags + leaf0);

    float l0 = (f.x & 0x000000FFu) ? oa.x : ta.x;
    float l1 = (f.x & 0x0000FF00u) ? oa.y : ta.y;
    float l2 = (f.x & 0x00FF0000u) ? oa.z : ta.z;
    float l3 = (f.x & 0xFF000000u) ? oa.w : ta.w;
    float l4 = (f.y & 0x000000FFu) ? ob.x : tb.x;
    float l5 = (f.y & 0x0000FF00u) ? ob.y : tb.y;
    float l6 = (f.y & 0x00FF0000u) ? ob.z : tb.z;
    float l7 = (f.y & 0xFF000000u) ? ob.w : tb.w;

    *(float4*)(out + C + leaf0)     = make_float4(l0, l1, l2, l3);
    *(float4*)(out + C + leaf0 + 4) = make_float4(l4, l5, l6, l7);

    // ---- L1 (4 nodes/thread) ----
    uint d10 = (f.x & 0x0000FFFFu) != 0u;
    uint d11 = (f.x & 0xFFFF0000u) != 0u;
    uint d12 = (f.y & 0x0000FFFFu) != 0u;
    uint d13 = (f.y & 0xFFFF0000u) != 0u;
    float4 t1 = *(const float4*)(tree + (C >> 1) + 4 * t);
    float4 v1;
    v1.x = d10 ? l0 + l1 : t1.x;
    v1.y = d11 ? l2 + l3 : t1.y;
    v1.z = d12 ? l4 + l5 : t1.z;
    v1.w = d13 ? l6 + l7 : t1.w;
    *(float4*)(out + (C >> 1) + 4 * t) = v1;

    // ---- L2 (2 nodes/thread) ----
    float2 t2 = *(const float2*)(tree + (C >> 2) + 2 * t);
    uint d20 = d10 | d11, d21 = d12 | d13;
    float2 v2;
    v2.x = d20 ? v1.x + v1.y : t2.x;
    v2.y = d21 ? v1.z + v1.w : t2.y;
    *(float2*)(out + (C >> 2) + 2 * t) = v2;

    // ---- L3 (1 node/thread) ----
    float t3 = tree[(C >> 3) + t];
    uint d3 = d20 | d21;
    float v3 = d3 ? v2.x + v2.y : t3;
    out[(C >> 3) + t] = v3;

    // ---- L4..L11: block-level LDS reduction (block = 2048 leaves) ----
    __shared__ float sv[256];
    __shared__ uint  sd[256];
    float curv = v3;
    uint  curd = d3;
    const int nb = blockIdx.x * 2048;   // first leaf (offset) of this block
    for (int lvl = 4; lvl <= 11; ++lvl) {
        sv[threadIdx.x] = curv;
        sd[threadIdx.x] = curd;
        __syncthreads();
        const int A = 2048 >> lvl;      // 128,64,...,1 active threads
        float nv = 0.f;
        uint  nd = 0u;
        if (threadIdx.x < A) {
            uint da = sd[2 * threadIdx.x], db = sd[2 * threadIdx.x + 1];
            nd = da | db;
            int node = (C >> lvl) + (nb >> lvl) + threadIdx.x;
            float tv = tree[node];
            nv = nd ? sv[2 * threadIdx.x] + sv[2 * threadIdx.x + 1] : tv;
            out[node] = nv;
        }
        __syncthreads();
        curv = nv;
        curd = nd;
    }
    if (threadIdx.x == 0) l11flag[blockIdx.x] = (uchar)curd;
}

// One block: L12..L23 (parents 2048 down to 1, 4095 nodes) + out[0] copy.
__global__ __launch_bounds__(1024)
void tail_kernel(const float* __restrict__ tree,
                 const uchar* __restrict__ l11flag,
                 float* __restrict__ out) {
    __shared__ float va[2048];
    __shared__ uint  da[2048];
    const int tid = threadIdx.x;
    // Level 12: parents [2048,4096); children = L11 nodes [4096,8192),
    // whose values were written by merge and dirty bits are l11flag[node-4096].
    for (int i = tid; i < 2048; i += 1024) {
        int p = 2048 + i;
        uint nd = (uint)l11flag[2 * i] | (uint)l11flag[2 * i + 1];
        float v = nd ? out[2 * p] + out[2 * p + 1] : tree[p];
        out[p] = v;
        va[i] = v;
        da[i] = nd;
    }
    __syncthreads();
    for (int M = 1024; M >= 1; M >>= 1) {
        float v = 0.f;
        uint  nd = 0u;
        if (tid < M) {
            int p = M + tid;
            nd = da[2 * tid] | da[2 * tid + 1];
            v = nd ? va[2 * tid] + va[2 * tid + 1] : tree[p];
            out[p] = v;
        }
        __syncthreads();
        if (tid < M) { va[tid] = v; da[tid] = nd; }
        __syncthreads();
    }
    if (tid == 0) out[0] = tree[0];
}

extern "C" void kernel_launch(void* const* d_in, const int* in_sizes, int n_in,
                              void* d_out, int out_size, void* d_ws, size_t ws_size,
                              hipStream_t stream) {
    const float* tree    = (const float*)d_in[0];
    const int*   indices = (const int*)d_in[1];
    const float* values  = (const float*)d_in[2];
    float* out = (float*)d_out;

    const int two_cap = in_sizes[0];     // 16,777,216
    const int C       = two_cap >> 1;    // 8,388,608
    const int n_upd   = in_sizes[1];     // 1,048,576

    float* overlay = (float*)d_ws;                         // 32 MiB
    uchar* flags   = (uchar*)d_ws + (size_t)C * 4;         // 8 MiB
    uchar* l11     = flags + C;                            // 4 KiB (fully rewritten)

    // 1. Clear leaf flags (ws is poisoned 0xAA each call).
    hipMemsetAsync(flags, 0, (size_t)C, stream);

    // 2. Scatter updates into overlay + flags (no atomics).
    scatter_kernel<<<(n_upd + 255) / 256, 256, 0, stream>>>(indices, values,
                                                            overlay, flags, n_upd);

    // 3. Fused copy + select + L1..L11 (tree read once, out written once).
    merge_kernel<<<C / 2048, 256, 0, stream>>>(tree, overlay, flags, l11, out, C);

    // 4. L12..L23 + out[0].
    tail_kernel<<<1, 1024, 0, stream>>>(tree, l11, out);
}